// Round 2
// baseline (293.140 us; speedup 1.0000x reference)
//
#include <hip/hip_runtime.h>

// GroupTokenizer: y [B,T,C] f32, edges [C,K] f32 -> labels [B,T,C] (as f32), reg [B,T,C,K] f32.
// B=32 T=4096 C=8 K=64. N = B*T*C = 1048576. Output = 272.6 MB -> streaming-store bound.
//
// R6: stream-shape fix. The rocclr fill sustains 6.27 TB/s at ~9% occupancy (≈800
// long contiguous write streams); R5 ran ~3.1 TB/s with 8192 grid-strided waves x
// 2 disjoint 16KB bursts each (row-buffer thrash from stream fragmentation).
// Now: 512 blocks x 8 waves; each block owns 32 CONTIGUOUS groups (512 KB), waves
// round-robin inside the block -> one quasi-sequential stream per block, 512 total.
// 2 blocks/CU = 16 waves/CU still hides the LDS search + vmcnt drain bubble.
// Store structure unchanged from R5: dependence-free -1 blast (memset-shaped),
// search overlaps drain, 1-dword delta scatter merges into dirty L2 lines after
// s_waitcnt vmcnt(0).
#define N_ELEM (32 * 4096 * 8)
#define CCH 8
#define KB 64
#define GROUPS_PER_BLOCK 32
#define THREADS 512

typedef float vfloat4 __attribute__((ext_vector_type(4)));

__global__ __launch_bounds__(THREADS) void group_tokenizer_kernel(
    const float* __restrict__ y,
    const float* __restrict__ le,
    const float* __restrict__ re,
    float* __restrict__ out,
    int ngroups) {
  // Edges in LDS, stride K+1=65 so bank = (c + k) % 32 (distinct across the 8 channels;
  // same-channel lanes hit identical addresses -> broadcast, free).
  __shared__ float ls[CCH][KB + 1];
  __shared__ float rs[CCH][KB + 1];
  const int tid = threadIdx.x;
  if (tid < CCH * KB) {                 // 512 threads cover all 512 edges in one step
    ls[tid >> 6][tid & 63] = le[tid];
    rs[tid >> 6][tid & 63] = re[tid];
  }
  __syncthreads();

  const int lane = tid & 63;
  const int wid = tid >> 6;                 // 0..7
  const int wavesPerBlock = THREADS >> 6;   // 8

  const vfloat4 neg1 = {-1.0f, -1.0f, -1.0f, -1.0f};
  const int base = blockIdx.x * GROUPS_PER_BLOCK;

  for (int gi = wid; gi < GROUPS_PER_BLOCK; gi += wavesPerBlock) {
    const int g = base + gi;
    if (g >= ngroups) break;

    const int e = g * 64 + lane;           // element index (lane-contiguous)
    const float yv = y[e];                 // independent of stores; issues early

    // Bulk phase: wave tile = 64 elems * 64 bins = 16 KB contiguous. 16 fully-coalesced,
    // dependence-free float4 stores of -1 (1 KB/instr/wave, full lines). Neighboring
    // waves of this block write the adjacent 16 KB tiles -> block-level sequential stream.
    float* regbase = out + (size_t)N_ELEM + (size_t)g * (64 * KB);
    vfloat4* regv = (vfloat4*)regbase;
#pragma unroll
    for (int j = 0; j < 16; ++j) {
      regv[(j << 6) + lane] = neg1;
    }

    // Compute phase (overlaps the store drain): binary search in LDS.
    const int c = e & (CCH - 1);           // e % 8 == lane % 8 (group base divisible by 64)
    const float* lr = ls[c];
    const float* rr = rs[c];

    // lower_bound on r: first k with yv < r[k]. 65 possible answers (0..64) ->
    // SEVEN branchless steps (6 left a size-1 interval untested -> earlier absmax bug).
    int lo = 0, hi = KB;
#pragma unroll
    for (int it = 0; it < 7; ++it) {
      const int mid = (lo + hi) >> 1;
      const bool cond = yv < rr[mid];
      hi = cond ? mid : hi;
      lo = cond ? lo : mid + 1;
    }
    // in_bin[lo] iff yv >= l[lo]; otherwise no bin anywhere -> label K-1.
    // (lo==KB read is safe: arrays padded to KB+1.)
    const int label = (lo < KB && yv >= lr[lo]) ? lo : (KB - 1);

    const float left = lr[label];
    const float right = rr[label];
    const float width = fmaxf(right - left, 1e-12f);
    float delta = (yv - left) / width;
    delta = fminf(fmaxf(delta, 0.0f), 1.0f);

    // labels output (as float), coalesced 4B/lane.
    out[e] = (float)label;

    // Order the delta scatter after this wave's -1 tile stores (same-wave same-address
    // WAW). After vmcnt(0) the -1 writes are at this XCD's L2 (point of coherence);
    // the scatter below hits the same dirty lines and merges there.
    asm volatile("s_waitcnt vmcnt(0)" ::: "memory");

    // Sparse phase: one dword per lane at [elem=lane][k=label]. 64 scattered dwords
    // across the wave's own 16 KB tile -> all L2 hits, negligible issue cost.
    regbase[(lane << 6) + label] = delta;
  }
}

extern "C" void kernel_launch(void* const* d_in, const int* in_sizes, int n_in,
                              void* d_out, int out_size, void* d_ws, size_t ws_size,
                              hipStream_t stream) {
  const float* y = (const float*)d_in[0];
  const float* le = (const float*)d_in[1];
  const float* re = (const float*)d_in[2];
  float* out = (float*)d_out;

  const int n = in_sizes[0];          // 1048576
  const int ngroups = n / 64;         // 16384 wave-tiles
  const int blocks = (ngroups + GROUPS_PER_BLOCK - 1) / GROUPS_PER_BLOCK;  // 512

  group_tokenizer_kernel<<<blocks, THREADS, 0, stream>>>(y, le, re, out, ngroups);
}

// Round 3
// 273.922 us; speedup vs baseline: 1.0702x; 1.0702x over previous
//
#include <hip/hip_runtime.h>

// GroupTokenizer: y [B,T,C] f32, edges [C,K] f32 -> labels [B,T,C] (as f32), reg [B,T,C,K] f32.
// B=32 T=4096 C=8 K=64. N = B*T*C = 1048576. Output = 272.6 MB -> streaming-store bound.
//
// R7: long continuous store streams, no drains. History:
//   R4 (shuffle-compose, 1 group/wave, 8192 waves): kernel ~89 us (~3.1 TB/s)
//   R5 (blast+scatter+vmcnt(0), 32 waves/CU):       kernel ~85 us (neutral)
//   R6 (blast+scatter, 16 waves/CU, contiguous):    kernel ~113 us (drain convoy at low TLP)
// Harness fill proves 6.1 TB/s pure-write on this buffer. Hypothesis: our store issue
// is bursty (16 stores, then ~400cy dependent search stall) and wave-streams are short
// (16 KB x 8192). This version: each wave owns 4 CONTIGUOUS groups; phase A computes
// all 4 searches up front (independent, ILP); phase B emits 4 label-line stores + 64
// back-to-back dwordx4 stores (65 KB continuous stream, shuffle/select gaps only).
// No vmcnt waits anywhere (shuffle-composed full-line stores, no WAW).
#define N_ELEM (32 * 4096 * 8)
#define CCH 8
#define KB 64
#define GPW 4   // contiguous groups per wave
#define WPB 4   // waves per block (256 threads)

typedef float vfloat4 __attribute__((ext_vector_type(4)));

__global__ __launch_bounds__(256) void group_tokenizer_kernel(
    const float* __restrict__ y,
    const float* __restrict__ le,
    const float* __restrict__ re,
    float* __restrict__ out,
    int ngroups) {
  // Edges in LDS, stride K+1=65 so bank = (c + k) % 32 (distinct across the 8 channels;
  // same-channel lanes hit identical addresses -> broadcast, free).
  __shared__ float ls[CCH][KB + 1];
  __shared__ float rs[CCH][KB + 1];
  const int tid = threadIdx.x;
  for (int t = tid; t < CCH * KB; t += blockDim.x) {
    ls[t >> 6][t & 63] = le[t];
    rs[t >> 6][t & 63] = re[t];
  }
  __syncthreads();

  const int lane = tid & 63;
  const int wid = tid >> 6;
  // Wave owns GPW contiguous groups; block owns WPB*GPW contiguous (260 KB stream).
  const int g0 = (blockIdx.x * WPB + wid) * GPW;
  if (g0 >= ngroups) return;

  const int c = lane & (CCH - 1);      // e % 8 == lane % 8 (group base divisible by 64)
  const float* lr = ls[c];
  const float* rr = rs[c];

  // ---- Phase A: all GPW searches up front (independent -> ILP, loads coalesced).
  int label4[GPW];
  float delta4[GPW];
#pragma unroll
  for (int t = 0; t < GPW; ++t) {
    const int g = g0 + t;
    const float yv = (g < ngroups) ? y[g * 64 + lane] : 0.0f;

    // lower_bound on r: first k with yv < r[k]. 65 possible answers (0..64) ->
    // SEVEN branchless steps (6 left a size-1 interval untested -> earlier absmax bug).
    int lo = 0, hi = KB;
#pragma unroll
    for (int it = 0; it < 7; ++it) {
      const int mid = (lo + hi) >> 1;
      const bool cond = yv < rr[mid];
      hi = cond ? mid : hi;
      lo = cond ? lo : mid + 1;
    }
    // in_bin[lo] iff yv >= l[lo]; otherwise no bin anywhere -> label K-1.
    // (lo==KB read is safe: arrays padded to KB+1.)
    const int label = (lo < KB && yv >= lr[lo]) ? lo : (KB - 1);
    const float left = lr[label];
    const float width = fmaxf(rr[label] - left, 1e-12f);
    label4[t] = label;
    delta4[t] = fminf(fmaxf((yv - left) / width, 0.0f), 1.0f);
  }

  // ---- Phase B: one long store burst. 4 label lines + 64 dwordx4 (65 KB contiguous).
#pragma unroll
  for (int t = 0; t < GPW; ++t) {
    const int g = g0 + t;
    if (g >= ngroups) break;
    out[g * 64 + lane] = (float)label4[t];
  }

  const int kst = (lane & 15) << 2;    // this lane's k-offset within its element
#pragma unroll
  for (int t = 0; t < GPW; ++t) {
    const int g = g0 + t;
    if (g >= ngroups) break;
    vfloat4* regv = (vfloat4*)(out + (size_t)N_ELEM + (size_t)g * (64 * KB));
    const int label = label4[t];
    const float delta = delta4[t];
#pragma unroll
    for (int j = 0; j < 16; ++j) {
      const int src = (j << 2) + (lane >> 4);   // which lane's element this float4 belongs to
      const int lbl = __shfl(label, src, 64);
      const float dlt = __shfl(delta, src, 64);
      vfloat4 v;
      v.x = (kst + 0 == lbl) ? dlt : -1.0f;
      v.y = (kst + 1 == lbl) ? dlt : -1.0f;
      v.z = (kst + 2 == lbl) ? dlt : -1.0f;
      v.w = (kst + 3 == lbl) ? dlt : -1.0f;
      regv[(j << 6) + lane] = v;
    }
  }
}

extern "C" void kernel_launch(void* const* d_in, const int* in_sizes, int n_in,
                              void* d_out, int out_size, void* d_ws, size_t ws_size,
                              hipStream_t stream) {
  const float* y = (const float*)d_in[0];
  const float* le = (const float*)d_in[1];
  const float* re = (const float*)d_in[2];
  float* out = (float*)d_out;

  const int n = in_sizes[0];          // 1048576
  const int ngroups = n / 64;         // 16384 wave-tiles
  const int gpb = WPB * GPW;          // 16 groups per block
  const int blocks = (ngroups + gpb - 1) / gpb;  // 1024 -> 16 waves/CU, 4/SIMD

  group_tokenizer_kernel<<<blocks, 256, 0, stream>>>(y, le, re, out, ngroups);
}

// Round 4
// 266.201 us; speedup vs baseline: 1.1012x; 1.0290x over previous
//
#include <hip/hip_runtime.h>

// GroupTokenizer: y [B,T,C] f32, edges [C,K] f32 -> labels [B,T,C] (as f32), reg [B,T,C,K] f32.
// B=32 T=4096 C=8 K=64. N = B*T*C = 1048576. Output = 272.6 MB -> streaming-store bound.
//
// R8: phase-split ILP at FULL occupancy. Occupancy matrix from R4-R7 (kernel-portion us,
// normalized against each run's rocclr-fill reference):
//   32 w/CU: R4 interleaved-compose 91, R5 blast+scatter 85
//   16 w/CU: R6 blast+scatter 113,      R7 phase-split  104
// -> TLP dominates; stream shape/continuity theories falsified. This version fills the
// remaining cell: 2048 blocks (exactly 8 blk/CU = 32 w/CU resident), 2 groups/wave,
// BOTH y-loads + BOTH 7-deep LDS searches interleaved up front (independent chains ->
// front-end bubble per group halves), then one 33-store burst (2 label lines + 32
// composed dwordx4). Shuffle-compose only: pure full-line writes, no scatter, no
// vmcnt drains, no RMW.
#define N_ELEM (32 * 4096 * 8)
#define CCH 8
#define KB 64
#define GPW 2   // groups per wave (2048 blocks x 4 waves x 2 = 16384 groups exactly)
#define WPB 4   // waves per block (256 threads)

typedef float vfloat4 __attribute__((ext_vector_type(4)));

__global__ __launch_bounds__(256) void group_tokenizer_kernel(
    const float* __restrict__ y,
    const float* __restrict__ le,
    const float* __restrict__ re,
    float* __restrict__ out,
    int ngroups) {
  // Edges in LDS, stride K+1=65 so bank = (c + k) % 32 (distinct across the 8 channels;
  // same-channel lanes hit identical addresses -> broadcast, free).
  __shared__ float ls[CCH][KB + 1];
  __shared__ float rs[CCH][KB + 1];
  const int tid = threadIdx.x;
  for (int t = tid; t < CCH * KB; t += blockDim.x) {
    ls[t >> 6][t & 63] = le[t];
    rs[t >> 6][t & 63] = re[t];
  }
  __syncthreads();

  const int lane = tid & 63;
  const int wid = tid >> 6;
  const int g0 = (blockIdx.x * WPB + wid) * GPW;
  if (g0 >= ngroups) return;

  const int c = lane & (CCH - 1);      // e % 8 == lane % 8 (group base divisible by 64)
  const float* lr = ls[c];
  const float* rr = rs[c];

  // ---- Phase A: both y-loads in flight together, then both searches interleaved
  // (independent 7-deep LDS chains overlap -> ~half the exposed search latency).
  int labelA[GPW];
  float deltaA[GPW];
#pragma unroll
  for (int t = 0; t < GPW; ++t) {
    const int g = g0 + t;
    const float yv = (g < ngroups) ? y[g * 64 + lane] : 0.0f;

    // lower_bound on r: first k with yv < r[k]. 65 possible answers (0..64) ->
    // SEVEN branchless steps (6 left a size-1 interval untested -> earlier absmax bug).
    int lo = 0, hi = KB;
#pragma unroll
    for (int it = 0; it < 7; ++it) {
      const int mid = (lo + hi) >> 1;
      const bool cond = yv < rr[mid];
      hi = cond ? mid : hi;
      lo = cond ? lo : mid + 1;
    }
    // in_bin[lo] iff yv >= l[lo]; otherwise no bin anywhere -> label K-1.
    // (lo==KB read is safe: arrays padded to KB+1.)
    const int label = (lo < KB && yv >= lr[lo]) ? lo : (KB - 1);
    const float left = lr[label];
    const float width = fmaxf(rr[label] - left, 1e-12f);
    labelA[t] = label;
    deltaA[t] = fminf(fmaxf((yv - left) / width, 0.0f), 1.0f);
  }

  // ---- Phase B: one store burst. 2 label lines + 32 composed dwordx4 (32.5 KB).
#pragma unroll
  for (int t = 0; t < GPW; ++t) {
    const int g = g0 + t;
    if (g < ngroups) out[g * 64 + lane] = (float)labelA[t];
  }

  const int kst = (lane & 15) << 2;    // this lane's k-offset within its element
#pragma unroll
  for (int t = 0; t < GPW; ++t) {
    const int g = g0 + t;
    if (g >= ngroups) break;
    vfloat4* regv = (vfloat4*)(out + (size_t)N_ELEM + (size_t)g * (64 * KB));
    const int label = labelA[t];
    const float delta = deltaA[t];
#pragma unroll
    for (int j = 0; j < 16; ++j) {
      const int src = (j << 2) + (lane >> 4);   // which lane's element this float4 belongs to
      const int lbl = __shfl(label, src, 64);
      const float dlt = __shfl(delta, src, 64);
      vfloat4 v;
      v.x = (kst + 0 == lbl) ? dlt : -1.0f;
      v.y = (kst + 1 == lbl) ? dlt : -1.0f;
      v.z = (kst + 2 == lbl) ? dlt : -1.0f;
      v.w = (kst + 3 == lbl) ? dlt : -1.0f;
      regv[(j << 6) + lane] = v;
    }
  }
}

extern "C" void kernel_launch(void* const* d_in, const int* in_sizes, int n_in,
                              void* d_out, int out_size, void* d_ws, size_t ws_size,
                              hipStream_t stream) {
  const float* y = (const float*)d_in[0];
  const float* le = (const float*)d_in[1];
  const float* re = (const float*)d_in[2];
  float* out = (float*)d_out;

  const int n = in_sizes[0];          // 1048576
  const int ngroups = n / 64;         // 16384 wave-tiles
  const int gpb = WPB * GPW;          // 8 groups per block
  const int blocks = (ngroups + gpb - 1) / gpb;  // 2048 -> exactly 8 blk/CU, 32 w/CU

  group_tokenizer_kernel<<<blocks, 256, 0, stream>>>(y, le, re, out, ngroups);
}